// Round 5
// baseline (276.019 us; speedup 1.0000x reference)
//
#include <hip/hip_runtime.h>
#include <math.h>

// EdgeGAT: B=8, OP=400, MA=200, F=64. f32 in/out, adj int32.
// Flash-style split over n: 4 chunks x 100 rows, z rows register-resident.
// Masked rows (adj==0, ~50%) are skipped entirely: no z/x load, no dot.
#define B_   8
#define OP_  400
#define MA_  200
#define NCH  4            // n-chunks per (b,m) row
#define CH   100          // rows per chunk
#define RPW  25           // rows per wave (CH / 4 waves)
#define PSTR 132          // partial stride: v[64] u[64] M L (+2 pad)
#define NEGM -1.0e30f     // finite mask sentinel

// ---------------- kernel 1: precompute (wave-per-row) ----------------
// w_e = W_edge@a_edge ; e_op[b,n] = x[b,n,:].(W_op@a_op) ; e_ma[b,m] = y[b,m,:].(W_ma@a_ma)
__global__ __launch_bounds__(256) void precompute_k(
    const float* __restrict__ x, const float* __restrict__ y,
    const float* __restrict__ Wop, const float* __restrict__ Wma,
    const float* __restrict__ Wedge, const float* __restrict__ att,
    float* __restrict__ ws_we, float* __restrict__ ws_eop, float* __restrict__ ws_ema)
{
    __shared__ float w_s[192];
    const int tid = threadIdx.x, wv = tid >> 6, ln = tid & 63;
    if (tid < 192) {
        const int which = tid >> 6, i = tid & 63;
        const float* W = (which == 0) ? Wop : ((which == 1) ? Wma : Wedge);
        const float* a = att + which * 64;
        float acc = 0.f;
        #pragma unroll 8
        for (int f = 0; f < 64; ++f) acc = fmaf(W[i * 64 + f], a[f], acc);
        w_s[tid] = acc;
    }
    __syncthreads();
    if (blockIdx.x == 0 && tid < 64) ws_we[tid] = w_s[128 + tid];

    const int row = blockIdx.x * 4 + wv;           // 0 .. 4799
    if (row < B_ * OP_) {
        float s = x[(size_t)row * 64 + ln] * w_s[ln];
        #pragma unroll
        for (int o = 32; o > 0; o >>= 1) s += __shfl_xor(s, o, 64);
        if (ln == 0) ws_eop[row] = s;
    } else if (row < B_ * OP_ + B_ * MA_) {
        const int r2 = row - B_ * OP_;
        float s = y[(size_t)r2 * 64 + ln] * w_s[64 + ln];
        #pragma unroll
        for (int o = 32; o > 0; o >>= 1) s += __shfl_xor(s, o, 64);
        if (ln == 0) ws_ema[r2] = s;
    }
}

// ---------------- kernel 2: chunk partials (block = (b,m,chunk)) ----------------
__global__ __launch_bounds__(256) void gat_chunk(
    const float* __restrict__ x, const float* __restrict__ z,
    const int* __restrict__ adj,
    const float* __restrict__ ws_we, const float* __restrict__ ws_eop,
    const float* __restrict__ ws_ema, float* __restrict__ part)
{
    __shared__ int   act[CH];
    __shared__ float s_arr[CH];
    __shared__ float red[8];
    __shared__ float vred[4][64];
    __shared__ float ured[4][64];

    const int tid = threadIdx.x, wv = tid >> 6, ln = tid & 63;
    const int blk = blockIdx.x;                 // bm * NCH + c
    const int bm = blk / NCH, c = blk % NCH;
    const int b = bm / MA_, m = bm % MA_;
    const int n0 = c * CH;
    const int nbase = wv * RPW;                 // this wave's rows within chunk

    // ---- adjacency first: active flags decide which rows we even touch ----
    if (tid < CH) {
        const int n = n0 + tid;
        act[tid]   = adj[((size_t)(b * OP_ + n)) * MA_ + m];
        s_arr[tid] = NEGM;
    }
    const float wel = ws_we[ln];                // per-lane, L2-resident
    const float ema = ws_ema[bm];
    __syncthreads();

    // ---- predicated loads: only active rows touch HBM (z) / L2 (x) ----
    const float* zb = z + ((size_t)(b * OP_ + n0) * MA_ + m) * 64;
    const float* xb = x + (size_t)(b * OP_ + n0) * 64;
    float zreg[RPW], xreg[RPW];
    #pragma unroll
    for (int i = 0; i < RPW; ++i) {
        const int n = nbase + i;
        const bool a = (act[n] != 0);           // wave-uniform branch
        zreg[i] = a ? zb[(size_t)n * (MA_ * 64) + ln] : 0.f;
        xreg[i] = a ? xb[(size_t)n * 64 + ln]         : 0.f;
    }

    // ---- scores for active rows only: dot + leaky_relu + e-terms fused ----
    #pragma unroll
    for (int i = 0; i < RPW; ++i) {
        const int n = nbase + i;
        if (act[n] != 0) {
            float s = zreg[i] * wel;
            #pragma unroll
            for (int o = 32; o > 0; o >>= 1) s += __shfl_xor(s, o, 64);
            if (ln == 0) {
                float e = s + ws_eop[b * OP_ + n0 + n] + ema;
                s_arr[n] = (e >= 0.f) ? e : 0.01f * e;
            }
        }
    }
    __syncthreads();

    // ---- chunk max ----
    float lm = NEGM;
    for (int n = tid; n < CH; n += 256) lm = fmaxf(lm, s_arr[n]);
    #pragma unroll
    for (int o = 32; o > 0; o >>= 1) lm = fmaxf(lm, __shfl_xor(lm, o, 64));
    if (ln == 0) red[wv] = lm;
    __syncthreads();
    const float M = fmaxf(fmaxf(red[0], red[1]), fmaxf(red[2], red[3]));

    // ---- p = exp(s - M) for active rows, partial sum L ----
    float ls = 0.f;
    for (int n = tid; n < CH; n += 256) {
        const float p = (act[n] != 0) ? __expf(s_arr[n] - M) : 0.f;
        s_arr[n] = p;
        ls += p;
    }
    #pragma unroll
    for (int o = 32; o > 0; o >>= 1) ls += __shfl_xor(ls, o, 64);
    if (ln == 0) red[4 + wv] = ls;
    __syncthreads();
    const float L = red[4] + red[5] + red[6] + red[7];

    // ---- v = sum p*z, u = sum p*x (registers, active rows only) ----
    float v = 0.f, u = 0.f;
    #pragma unroll
    for (int i = 0; i < RPW; ++i) {
        const int n = nbase + i;
        if (act[n] != 0) {
            const float p = s_arr[n];           // LDS broadcast
            v = fmaf(p, zreg[i], v);
            u = fmaf(p, xreg[i], u);
        }
    }
    vred[wv][ln] = v; ured[wv][ln] = u;
    __syncthreads();

    // ---- write partial: v[64] u[64] M L ----
    float* pp = part + (size_t)blk * PSTR;
    if (tid < 64)        pp[tid] = vred[0][tid] + vred[1][tid] + vred[2][tid] + vred[3][tid];
    else if (tid < 128)  pp[tid] = ured[0][tid-64] + ured[1][tid-64] + ured[2][tid-64] + ured[3][tid-64];
    else if (tid == 128) { pp[128] = M; pp[129] = L; }
}

// ---------------- kernel 3: combine + epilogue (wave per (b,m) row) ----------------
__global__ __launch_bounds__(256) void gat_combine(
    const float* __restrict__ y,
    const float* __restrict__ Wop, const float* __restrict__ Wma,
    const float* __restrict__ Wedge,
    const float* __restrict__ part, float* __restrict__ out)
{
    __shared__ float vs[4][64], us[4][64], ys[4][64];
    const int tid = threadIdx.x, wv = tid >> 6, ln = tid & 63;
    const int row = blockIdx.x * 4 + wv;        // bm, grid covers 1600 exactly

    const float* pp = part + (size_t)row * NCH * PSTR;
    float M = NEGM;
    #pragma unroll
    for (int c = 0; c < NCH; ++c) M = fmaxf(M, pp[c * PSTR + 128]);
    float L = 0.f, v = 0.f, u = 0.f;
    #pragma unroll
    for (int c = 0; c < NCH; ++c) {
        const float Mc = pp[c * PSTR + 128];
        const float w  = (Mc > -1.0e29f) ? __expf(Mc - M) : 0.f;
        L += w * pp[c * PSTR + 129];
        v += w * pp[c * PSTR + ln];
        u += w * pp[c * PSTR + 64 + ln];
    }
    const float inv = (L > 0.f) ? (1.f / L) : 0.f;
    vs[wv][ln] = v * inv;
    us[wv][ln] = u * inv;
    ys[wv][ln] = y[(size_t)row * 64 + ln];
    __syncthreads();

    float hv = 0.f;
    #pragma unroll 8
    for (int i = 0; i < 64; ++i) {
        hv += vs[wv][i] * Wedge[i * 64 + ln]
            + us[wv][i] * Wop[i * 64 + ln]
            + ys[wv][i] * Wma[i * 64 + ln];
    }
    out[(size_t)row * 64 + ln] = (hv > 0.f) ? hv : (__expf(hv) - 1.f);
}

extern "C" void kernel_launch(void* const* d_in, const int* in_sizes, int n_in,
                              void* d_out, int out_size, void* d_ws, size_t ws_size,
                              hipStream_t stream) {
    const float* x     = (const float*)d_in[0];
    const float* y     = (const float*)d_in[1];
    const float* z     = (const float*)d_in[2];
    const int*   adj   = (const int*)d_in[3];
    const float* Wop   = (const float*)d_in[4];
    const float* Wma   = (const float*)d_in[5];
    const float* Wedge = (const float*)d_in[6];
    const float* att   = (const float*)d_in[7];

    float* ws     = (float*)d_ws;
    float* ws_we  = ws;                              // 64
    float* ws_eop = ws + 64;                         // B*OP = 3200
    float* ws_ema = ws + 64 + B_ * OP_;              // B*MA = 1600
    float* part   = ws + 64 + B_ * OP_ + B_ * MA_;   // 6400 * 132 = 844800

    precompute_k<<<1200, 256, 0, stream>>>(
        x, y, Wop, Wma, Wedge, att, ws_we, ws_eop, ws_ema);
    gat_chunk<<<B_ * MA_ * NCH, 256, 0, stream>>>(
        x, z, adj, ws_we, ws_eop, ws_ema, part);
    gat_combine<<<(B_ * MA_) / 4, 256, 0, stream>>>(
        y, Wop, Wma, Wedge, part, (float*)d_out);
}

// Round 6
// 261.939 us; speedup vs baseline: 1.0538x; 1.0538x over previous
//
#include <hip/hip_runtime.h>
#include <math.h>

// EdgeGAT: B=8, OP=400, MA=200, F=64. f32 in/out, adj int32.
// Flash-style split over n: 4 chunks x 100 rows.
// Score pass: quad-per-row layout (r=lane>>2, g=lane&3), 16-wide reg dot +
// 2 quad shuffles (DPP) -- replaces 150 LDS-pipe shuffles per wave.
// v/u pass: lane=feature layout, z re-read hits L2.
#define B_   8
#define OP_  400
#define MA_  200
#define NCH  4            // n-chunks per (b,m) row
#define CH   100          // rows per chunk
#define RPW  25           // rows per wave (CH / 4 waves)
#define PSTR 132          // partial stride: v[64] u[64] M L (+2 pad)
#define NEGM -1.0e30f     // finite mask sentinel

// ---------------- kernel 1: precompute (wave-per-row) ----------------
// w_e = W_edge@a_edge ; e_op[b,n] = x[b,n,:].(W_op@a_op) ; e_ma[b,m] = y[b,m,:].(W_ma@a_ma)
__global__ __launch_bounds__(256) void precompute_k(
    const float* __restrict__ x, const float* __restrict__ y,
    const float* __restrict__ Wop, const float* __restrict__ Wma,
    const float* __restrict__ Wedge, const float* __restrict__ att,
    float* __restrict__ ws_we, float* __restrict__ ws_eop, float* __restrict__ ws_ema)
{
    __shared__ float w_s[192];
    const int tid = threadIdx.x, wv = tid >> 6, ln = tid & 63;
    if (tid < 192) {
        const int which = tid >> 6, i = tid & 63;
        const float* W = (which == 0) ? Wop : ((which == 1) ? Wma : Wedge);
        const float* a = att + which * 64;
        float acc = 0.f;
        #pragma unroll 8
        for (int f = 0; f < 64; ++f) acc = fmaf(W[i * 64 + f], a[f], acc);
        w_s[tid] = acc;
    }
    __syncthreads();
    if (blockIdx.x == 0 && tid < 64) ws_we[tid] = w_s[128 + tid];

    const int row = blockIdx.x * 4 + wv;           // 0 .. 4799
    if (row < B_ * OP_) {
        float s = x[(size_t)row * 64 + ln] * w_s[ln];
        #pragma unroll
        for (int o = 32; o > 0; o >>= 1) s += __shfl_xor(s, o, 64);
        if (ln == 0) ws_eop[row] = s;
    } else if (row < B_ * OP_ + B_ * MA_) {
        const int r2 = row - B_ * OP_;
        float s = y[(size_t)r2 * 64 + ln] * w_s[64 + ln];
        #pragma unroll
        for (int o = 32; o > 0; o >>= 1) s += __shfl_xor(s, o, 64);
        if (ln == 0) ws_ema[r2] = s;
    }
}

// ---------------- kernel 2: chunk partials (block = (b,m,chunk)) ----------------
__global__ __launch_bounds__(256) void gat_chunk(
    const float* __restrict__ x, const float* __restrict__ z,
    const int* __restrict__ adj,
    const float* __restrict__ ws_we, const float* __restrict__ ws_eop,
    const float* __restrict__ ws_ema, float* __restrict__ part)
{
    __shared__ int    act[CH];
    __shared__ float  s_arr[CH];
    __shared__ float  red[8];
    __shared__ float4 we4[16];          // w_e, 16B-aligned for float4 LDS reads
    __shared__ float  vred[4][64];
    __shared__ float  ured[4][64];

    const int tid = threadIdx.x, wv = tid >> 6, ln = tid & 63;
    const int blk = blockIdx.x;                 // bm * NCH + c
    const int bm = blk / NCH, c = blk % NCH;
    const int b = bm / MA_, m = bm % MA_;
    const int n0 = c * CH;
    const int nbase = wv * RPW;                 // this wave's first row in chunk

    // ---- stage adjacency + w_e; init scores to sentinel ----
    if (tid < CH) {
        const int n = n0 + tid;
        act[tid]   = adj[((size_t)(b * OP_ + n)) * MA_ + m];
        s_arr[tid] = NEGM;
    }
    if (tid < 64) ((float*)we4)[tid] = ws_we[tid];
    const float ema = ws_ema[bm];
    __syncthreads();

    const float* zb = z + ((size_t)(b * OP_ + n0) * MA_ + m) * 64;
    const float* xb = x + (size_t)(b * OP_ + n0) * 64;

    // ---- score pass: quad-per-row layout. 16-wide reg dot + xor1/xor2 ----
    const int r = ln >> 2, g = ln & 3;
    const float4 w0 = we4[g * 4 + 0], w1 = we4[g * 4 + 1];
    const float4 w2 = we4[g * 4 + 2], w3 = we4[g * 4 + 3];
    #pragma unroll
    for (int batch = 0; batch < 2; ++batch) {
        const int lrow = batch * 16 + r;          // local row within this wave
        const bool valid = (lrow < RPW);
        const int n = nbase + (valid ? lrow : 0); // clamped; masked below
        const bool a = valid && (act[n] != 0);    // per-lane predication
        float s = 0.f;
        if (a) {
            const float4* zr = (const float4*)(zb + (size_t)n * (MA_ * 64) + g * 16);
            float4 q0 = zr[0], q1 = zr[1], q2 = zr[2], q3 = zr[3];
            s = fmaf(q0.x, w0.x, fmaf(q0.y, w0.y, fmaf(q0.z, w0.z, q0.w * w0.w)));
            s = fmaf(q1.x, w1.x, fmaf(q1.y, w1.y, fmaf(q1.z, w1.z, fmaf(q1.w, w1.w, s))));
            s = fmaf(q2.x, w2.x, fmaf(q2.y, w2.y, fmaf(q2.z, w2.z, fmaf(q2.w, w2.w, s))));
            s = fmaf(q3.x, w3.x, fmaf(q3.y, w3.y, fmaf(q3.z, w3.z, fmaf(q3.w, w3.w, s))));
        }
        s += __shfl_xor(s, 1, 64);                // quad_perm (VALU DPP)
        s += __shfl_xor(s, 2, 64);
        if (a && g == 0) {
            float e = s + ws_eop[b * OP_ + n0 + n] + ema;
            s_arr[n] = (e >= 0.f) ? e : 0.01f * e;   // leaky_relu fused
        }
    }
    __syncthreads();

    // ---- chunk max ----
    float lm = NEGM;
    for (int n = tid; n < CH; n += 256) lm = fmaxf(lm, s_arr[n]);
    #pragma unroll
    for (int o = 32; o > 0; o >>= 1) lm = fmaxf(lm, __shfl_xor(lm, o, 64));
    if (ln == 0) red[wv] = lm;
    __syncthreads();
    const float M = fmaxf(fmaxf(red[0], red[1]), fmaxf(red[2], red[3]));

    // ---- p = exp(s - M) for active rows, partial sum L ----
    float ls = 0.f;
    for (int n = tid; n < CH; n += 256) {
        const float p = (act[n] != 0) ? __expf(s_arr[n] - M) : 0.f;
        s_arr[n] = p;
        ls += p;
    }
    #pragma unroll
    for (int o = 32; o > 0; o >>= 1) ls += __shfl_xor(ls, o, 64);
    if (ln == 0) red[4 + wv] = ls;
    __syncthreads();
    const float L = red[4] + red[5] + red[6] + red[7];

    // ---- v/u pass: lane=feature; z re-read hits L2 (just fetched above) ----
    float v = 0.f, u = 0.f;
    #pragma unroll
    for (int i = 0; i < RPW; ++i) {
        const int n = nbase + i;
        if (act[n] != 0) {                        // wave-uniform branch
            const float p = s_arr[n];             // LDS broadcast
            v = fmaf(p, zb[(size_t)n * (MA_ * 64) + ln], v);
            u = fmaf(p, xb[(size_t)n * 64 + ln], u);
        }
    }
    vred[wv][ln] = v; ured[wv][ln] = u;
    __syncthreads();

    // ---- write partial: v[64] u[64] M L ----
    float* pp = part + (size_t)blk * PSTR;
    if (tid < 64)        pp[tid] = vred[0][tid] + vred[1][tid] + vred[2][tid] + vred[3][tid];
    else if (tid < 128)  pp[tid] = ured[0][tid-64] + ured[1][tid-64] + ured[2][tid-64] + ured[3][tid-64];
    else if (tid == 128) { pp[128] = M; pp[129] = L; }
}

// ---------------- kernel 3: combine + epilogue (wave per (b,m) row) ----------------
__global__ __launch_bounds__(256) void gat_combine(
    const float* __restrict__ y,
    const float* __restrict__ Wop, const float* __restrict__ Wma,
    const float* __restrict__ Wedge,
    const float* __restrict__ part, float* __restrict__ out)
{
    __shared__ float vs[4][64], us[4][64], ys[4][64];
    const int tid = threadIdx.x, wv = tid >> 6, ln = tid & 63;
    const int row = blockIdx.x * 4 + wv;        // bm, grid covers 1600 exactly

    const float* pp = part + (size_t)row * NCH * PSTR;
    float M = NEGM;
    #pragma unroll
    for (int c = 0; c < NCH; ++c) M = fmaxf(M, pp[c * PSTR + 128]);
    float L = 0.f, v = 0.f, u = 0.f;
    #pragma unroll
    for (int c = 0; c < NCH; ++c) {
        const float Mc = pp[c * PSTR + 128];
        const float w  = (Mc > -1.0e29f) ? __expf(Mc - M) : 0.f;
        L += w * pp[c * PSTR + 129];
        v += w * pp[c * PSTR + ln];
        u += w * pp[c * PSTR + 64 + ln];
    }
    const float inv = (L > 0.f) ? (1.f / L) : 0.f;
    vs[wv][ln] = v * inv;
    us[wv][ln] = u * inv;
    ys[wv][ln] = y[(size_t)row * 64 + ln];
    __syncthreads();

    float hv = 0.f;
    #pragma unroll 8
    for (int i = 0; i < 64; ++i) {
        hv += vs[wv][i] * Wedge[i * 64 + ln]
            + us[wv][i] * Wop[i * 64 + ln]
            + ys[wv][i] * Wma[i * 64 + ln];
    }
    out[(size_t)row * 64 + ln] = (hv > 0.f) ? hv : (__expf(hv) - 1.f);
}

extern "C" void kernel_launch(void* const* d_in, const int* in_sizes, int n_in,
                              void* d_out, int out_size, void* d_ws, size_t ws_size,
                              hipStream_t stream) {
    const float* x     = (const float*)d_in[0];
    const float* y     = (const float*)d_in[1];
    const float* z     = (const float*)d_in[2];
    const int*   adj   = (const int*)d_in[3];
    const float* Wop   = (const float*)d_in[4];
    const float* Wma   = (const float*)d_in[5];
    const float* Wedge = (const float*)d_in[6];
    const float* att   = (const float*)d_in[7];

    float* ws     = (float*)d_ws;
    float* ws_we  = ws;                              // 64
    float* ws_eop = ws + 64;                         // B*OP = 3200
    float* ws_ema = ws + 64 + B_ * OP_;              // B*MA = 1600
    float* part   = ws + 64 + B_ * OP_ + B_ * MA_;   // 6400 * 132 = 844800

    precompute_k<<<1200, 256, 0, stream>>>(
        x, y, Wop, Wma, Wedge, att, ws_we, ws_eop, ws_ema);
    gat_chunk<<<B_ * MA_ * NCH, 256, 0, stream>>>(
        x, z, adj, ws_we, ws_eop, ws_ema, part);
    gat_combine<<<(B_ * MA_) / 4, 256, 0, stream>>>(
        y, Wop, Wma, Wedge, part, (float*)d_out);
}